// Round 15
// baseline (42.086 us; speedup 1.0000x reference)
//
#include <hip/hip_runtime.h>

// LearnableDCT as GEMM on matrix cores — 32x32x16 bf16, fused, 3-tile
// software-pipelined waves.
//
// Round-14 post-mortem: steady HBM = 98MB writes only (reads are L3 hits);
// floor ~14.3us at the fill kernel's 6.9 TB/s. We were 2.6x over with 6%
// MfmaUtil: one tiny tile per wave means per-wave startup latency x12288.
// Round 15: each wave owns 3 tiles, pipelined with NAMED register sets
// (rule #20): prefetch T0+T1 before the staging barrier, compute T0 || load
// T2, compute T1, compute T2. Grid 1024 WGs = exactly 4 resident WGs/CU
// (16 waves/CU), zero dispatch churn. launch_bounds(256,4) = 128-VGPR
// budget >= ~116 demand so regalloc keeps the pipeline.

typedef float  f32x16 __attribute__((ext_vector_type(16)));
typedef __bf16 bf16x8 __attribute__((ext_vector_type(8)));

static __device__ __forceinline__ f32x16 mfma32(bf16x8 a, bf16x8 b, f32x16 c) {
    return __builtin_amdgcn_mfma_f32_32x32x16_bf16(a, b, c, 0, 0, 0);
}

#define MAKE_BX(va, vb, XH, XL)                                        \
    {                                                                  \
        const float vv[8] = {va.x, va.y, va.z, va.w,                   \
                             vb.x, vb.y, vb.z, vb.w};                  \
        _Pragma("unroll")                                              \
        for (int j = 0; j < 8; ++j) {                                  \
            const __bf16 hh = (__bf16)vv[j];                           \
            XH[j] = hh;                                                \
            XL[j] = (__bf16)(vv[j] - (float)hh);                       \
        }                                                              \
    }

// tile T (0..12287): wb0=(T&1)*32, hb=(T>>1)&63, bc=T>>7
#define LOAD_TILE(T, XA, XB)                                              \
    {                                                                     \
        const int wb0_ = ((T) & 1) << 5;                                  \
        const int hb_  = ((T) >> 1) & 63;                                 \
        const int bc_  = (T) >> 7;                                        \
        const float* xp_ = x + ((size_t)bc_ << 18) + ((size_t)hb_ << 12)  \
                             + ((wb0_ + c31) << 3);                       \
        _Pragma("unroll")                                                 \
        for (int nc = 0; nc < 4; ++nc) {                                  \
            const int i_ = nc * 2 + half;                                 \
            XA[nc] = *reinterpret_cast<const float4*>(xp_ + i_ * 512);    \
            XB[nc] = *reinterpret_cast<const float4*>(xp_ + i_ * 512 + 4);\
        }                                                                 \
    }

#define ALD(F) Alds[((F) << 6) + lane]

#define COMPUTE_STORE(T, XA, XB)                                          \
    {                                                                     \
        f32x16 acc0 = {0.f}, acc1 = {0.f};                                \
        _Pragma("unroll")                                                 \
        for (int nc = 0; nc < 4; ++nc) {                                  \
            bf16x8 Xh, Xl;                                                \
            MAKE_BX(XA[nc], XB[nc], Xh, Xl)                               \
            acc0 = mfma32(ALD((0 * 4 + nc) * 2 + 0), Xh, acc0);           \
            acc1 = mfma32(ALD((1 * 4 + nc) * 2 + 0), Xh, acc1);           \
            acc0 = mfma32(ALD((0 * 4 + nc) * 2 + 0), Xl, acc0);           \
            acc1 = mfma32(ALD((1 * 4 + nc) * 2 + 0), Xl, acc1);           \
            acc0 = mfma32(ALD((0 * 4 + nc) * 2 + 1), Xh, acc0);           \
            acc1 = mfma32(ALD((1 * 4 + nc) * 2 + 1), Xh, acc1);           \
        }                                                                 \
        const int wb0_ = ((T) & 1) << 5;                                  \
        const int hb_  = ((T) >> 1) & 63;                                 \
        const int bc_  = (T) >> 7;                                        \
        float* ob_ = out + ((size_t)bc_ << 18) + (hb_ << 6) + wb0_ + c31; \
        _Pragma("unroll")                                                 \
        for (int r = 0; r < 16; ++r) {                                    \
            const int row = (r & 3) + ((r >> 2) << 3) + (half << 2);      \
            __builtin_nontemporal_store(acc0[r],                          \
                                        ob_ + ((size_t)row << 12));       \
            __builtin_nontemporal_store(acc1[r],                          \
                                        ob_ + ((size_t)(row + 32) << 12));\
        }                                                                 \
    }

__global__ __launch_bounds__(256, 4) void dct_mfma(
    const float* __restrict__ x,
    const float* __restrict__ basis,
    float* __restrict__ out)
{
    __shared__ bf16x8 Alds[16 * 64];   // [F][lane], 16 KB

    const int tid  = threadIdx.x;
    const int lane = tid & 63;
    const int wv   = tid >> 6;              // 0..3
    const int c31  = lane & 31;
    const int half = lane >> 5;             // 0/1

    const int W  = blockIdx.x * 4 + wv;     // wave id, 0..4095
    const int T0 = W * 3;                   // 3 consecutive tiles per wave

    // ---- prefetch tiles T0, T1 (latency hides under staging+barrier) ----
    float4 pa[4], pb[4], qa[4], qb[4];
    LOAD_TILE(T0,     pa, pb)
    LOAD_TILE(T0 + 1, qa, qb)

    // ---- stage hi/lo A-fragments into LDS (round-14 verified) ----
    // F=((kt*4+nc)*2+p): lane l elem j = basis[kt*32+(l&31)][nc*16+(l>>5)*8+j]
    #pragma unroll
    for (int r = 0; r < 4; ++r) {
        const int s  = tid + (r << 8);         // 0..1023
        const int F  = s >> 6;                 // wave-uniform
        const int ln = s & 63;
        const int k  = ((F >> 3) << 5) + (ln & 31);
        const int n  = (((F >> 1) & 3) << 4) + ((ln >> 5) << 3);
        const float4 v0 = *reinterpret_cast<const float4*>(basis + k * 64 + n);
        const float4 v1 = *reinterpret_cast<const float4*>(basis + k * 64 + n + 4);
        const float vv[8] = {v0.x, v0.y, v0.z, v0.w, v1.x, v1.y, v1.z, v1.w};
        bf16x8 f;
        if (F & 1) {
            #pragma unroll
            for (int j = 0; j < 8; ++j) {
                const __bf16 h = (__bf16)vv[j];
                f[j] = (__bf16)(vv[j] - (float)h);
            }
        } else {
            #pragma unroll
            for (int j = 0; j < 8; ++j)
                f[j] = (__bf16)vv[j];
        }
        Alds[s] = f;
    }
    __syncthreads();

    // ---- pipelined: compute T0 || load T2, compute T1, compute T2 ----
    COMPUTE_STORE(T0,     pa, pb)
    LOAD_TILE(T0 + 2, pa, pb)
    COMPUTE_STORE(T0 + 1, qa, qb)
    COMPUTE_STORE(T0 + 2, pa, pb)
}

extern "C" void kernel_launch(void* const* d_in, const int* in_sizes, int n_in,
                              void* d_out, int out_size, void* d_ws, size_t ws_size,
                              hipStream_t stream) {
    const float* x     = (const float*)d_in[0];
    const float* basis = (const float*)d_in[1];
    float* out         = (float*)d_out;

    // 12288 tiles / (4 waves * 3 tiles) = 1024 WGs = exactly 4 resident/CU
    dct_mfma<<<dim3(1024), dim3(256), 0, stream>>>(x, basis, out);
}

// Round 16
// 39.269 us; speedup vs baseline: 1.0717x; 1.0717x over previous
//
#include <hip/hip_runtime.h>

// LearnableDCT as GEMM on matrix cores — 32x32x16 bf16, fused staging,
// 12 tiles per WG in 3 write-paired stages.
//
// Round-15 post-mortem: T=W*3 broke write pairing — the two 128B halves of
// each 256B output row were written far apart in time -> partial-burst
// write amplification (WRITE 98.3 -> 120.8 MB, +23%) and proportional
// slowdown. Round 16: WG owns 12 consecutive tiles; stage s has the 4
// concurrent waves doing tiles {4s, 4s+1, 4s+2, 4s+3} = two COMPLETE
// (wb0=0,32) row pairs, restoring round-14's clean 98.3MB writes, while
// the 16KB A-staging is now amortized over 12 tiles instead of 4
// (1024 WGs vs 3072). Per-tile datapath unchanged (m74/m101 D-layout).

typedef float  f32x16 __attribute__((ext_vector_type(16)));
typedef __bf16 bf16x8 __attribute__((ext_vector_type(8)));

static __device__ __forceinline__ f32x16 mfma32(bf16x8 a, bf16x8 b, f32x16 c) {
    return __builtin_amdgcn_mfma_f32_32x32x16_bf16(a, b, c, 0, 0, 0);
}

#define MAKE_BX(va, vb, XH, XL)                                        \
    {                                                                  \
        const float vv[8] = {va.x, va.y, va.z, va.w,                   \
                             vb.x, vb.y, vb.z, vb.w};                  \
        _Pragma("unroll")                                              \
        for (int j = 0; j < 8; ++j) {                                  \
            const __bf16 hh = (__bf16)vv[j];                           \
            XH[j] = hh;                                                \
            XL[j] = (__bf16)(vv[j] - (float)hh);                       \
        }                                                              \
    }

__global__ __launch_bounds__(256) void dct_mfma(
    const float* __restrict__ x,
    const float* __restrict__ basis,
    float* __restrict__ out)
{
    __shared__ bf16x8 Alds[16 * 64];   // [F][lane], 16 KB

    const int tid  = threadIdx.x;
    const int lane = tid & 63;
    const int wv   = tid >> 6;              // 0..3
    const int c31  = lane & 31;
    const int half = lane >> 5;             // 0/1

    // ---- stage hi/lo A-fragments into LDS (round-14 verified) ----
    // F=((kt*4+nc)*2+p): lane l elem j = basis[kt*32+(l&31)][nc*16+(l>>5)*8+j]
    #pragma unroll
    for (int r = 0; r < 4; ++r) {
        const int s  = tid + (r << 8);         // 0..1023
        const int F  = s >> 6;                 // wave-uniform
        const int ln = s & 63;
        const int k  = ((F >> 3) << 5) + (ln & 31);
        const int n  = (((F >> 1) & 3) << 4) + ((ln >> 5) << 3);
        const float4 v0 = *reinterpret_cast<const float4*>(basis + k * 64 + n);
        const float4 v1 = *reinterpret_cast<const float4*>(basis + k * 64 + n + 4);
        const float vv[8] = {v0.x, v0.y, v0.z, v0.w, v1.x, v1.y, v1.z, v1.w};
        bf16x8 f;
        if (F & 1) {
            #pragma unroll
            for (int j = 0; j < 8; ++j) {
                const __bf16 h = (__bf16)vv[j];
                f[j] = (__bf16)(vv[j] - (float)h);
            }
        } else {
            #pragma unroll
            for (int j = 0; j < 8; ++j)
                f[j] = (__bf16)vv[j];
        }
        Alds[s] = f;
    }
    __syncthreads();

#define ALD(F) Alds[((F) << 6) + lane]

    // ---- 3 stages; at each stage the WG's 4 waves cover 4 consecutive
    // tiles = two complete (wb0=0,32) 256B row pairs (write pairing). ----
    const int Tb = blockIdx.x * 12;
    #pragma unroll 1
    for (int s = 0; s < 3; ++s) {
        const int T   = Tb + (s << 2) + wv;   // tile id, 0..12287
        const int wb0 = (T & 1) << 5;
        const int hb  = (T >> 1) & 63;
        const int bc  = T >> 7;               // 0..95

        // B: lane supplies x rows i = nc*2 + half of block wb0+c31
        const float* xp = x + ((size_t)bc << 18) + ((size_t)hb << 12)
                            + ((wb0 + c31) << 3);

        f32x16 acc0 = {0.f}, acc1 = {0.f};
        #pragma unroll
        for (int nc = 0; nc < 4; ++nc) {
            const int i = nc * 2 + half;
            const float4 a = *reinterpret_cast<const float4*>(xp + i * 512);
            const float4 b = *reinterpret_cast<const float4*>(xp + i * 512 + 4);
            bf16x8 Xh, Xl;
            MAKE_BX(a, b, Xh, Xl)
            acc0 = mfma32(ALD((0 * 4 + nc) * 2 + 0), Xh, acc0);  // bh*xh k0..31
            acc1 = mfma32(ALD((1 * 4 + nc) * 2 + 0), Xh, acc1);  // bh*xh k32..63
            acc0 = mfma32(ALD((0 * 4 + nc) * 2 + 0), Xl, acc0);  // bh*xl
            acc1 = mfma32(ALD((1 * 4 + nc) * 2 + 0), Xl, acc1);
            acc0 = mfma32(ALD((0 * 4 + nc) * 2 + 1), Xh, acc0);  // bl*xh
            acc1 = mfma32(ALD((1 * 4 + nc) * 2 + 1), Xh, acc1);
        }

        // D: reg r -> row (r&3)+8*(r>>2)+4*half, col c31; lanes 0..31 =
        // full 128B line, paired across the WG's waves to full 256B rows.
        float* ob = out + ((size_t)bc << 18) + (hb << 6) + wb0 + c31;
        #pragma unroll
        for (int r = 0; r < 16; ++r) {
            const int row = (r & 3) + ((r >> 2) << 3) + (half << 2);
            __builtin_nontemporal_store(acc0[r], ob + ((size_t)row << 12));
            __builtin_nontemporal_store(acc1[r], ob + ((size_t)(row + 32) << 12));
        }
    }
}

extern "C" void kernel_launch(void* const* d_in, const int* in_sizes, int n_in,
                              void* d_out, int out_size, void* d_ws, size_t ws_size,
                              hipStream_t stream) {
    const float* x     = (const float*)d_in[0];
    const float* basis = (const float*)d_in[1];
    float* out         = (float*)d_out;

    // 12288 tiles / 12 per WG = 1024 WGs (4 resident WGs/CU)
    dct_mfma<<<dim3(1024), dim3(256), 0, stream>>>(x, basis, out);
}

// Round 17
// 38.267 us; speedup vs baseline: 1.0998x; 1.0262x over previous
//
#include <hip/hip_runtime.h>

// LearnableDCT as GEMM on matrix cores — 32x32x16 bf16, fused staging,
// wave = FULL output row (both wb halves), WG = 4 consecutive hb.
//
// Rounds 8-16 post-mortem: all structures plateau at 37-42us, ~2.6 TB/s
// combined, while a pure fill sustains 7 TB/s at 9% occupancy. Diagnosis:
// store-stream DRAM-row locality. Our writes land 256B per (bc,k)-plane,
// and the 8 slices of each 2KB DRAM row come from 8 different WGs at
// random times -> one ACT/PRE per ~256B -> ~3x write-BW collapse. Fix:
// (1) one wave computes BOTH wb halves of an hb (4 accs) so each 256B
// k-row is written by adjacent instructions of one wave; (2) WG covers 4
// consecutive hb, so per k the WG emits ~1KB contiguous within a tight
// window. Datapath = R12-verified mapping, applied to blocks c31 and
// 32+c31.

typedef float  f32x16 __attribute__((ext_vector_type(16)));
typedef __bf16 bf16x8 __attribute__((ext_vector_type(8)));

static __device__ __forceinline__ f32x16 mfma32(bf16x8 a, bf16x8 b, f32x16 c) {
    return __builtin_amdgcn_mfma_f32_32x32x16_bf16(a, b, c, 0, 0, 0);
}

#define MAKE_BX(va, vb, XH, XL)                                        \
    {                                                                  \
        const float vv[8] = {va.x, va.y, va.z, va.w,                   \
                             vb.x, vb.y, vb.z, vb.w};                  \
        _Pragma("unroll")                                              \
        for (int j = 0; j < 8; ++j) {                                  \
            const __bf16 hh = (__bf16)vv[j];                           \
            XH[j] = hh;                                                \
            XL[j] = (__bf16)(vv[j] - (float)hh);                       \
        }                                                              \
    }

__global__ __launch_bounds__(256, 4) void dct_mfma(
    const float* __restrict__ x,
    const float* __restrict__ basis,
    float* __restrict__ out)
{
    __shared__ bf16x8 Alds[16 * 64];   // [F][lane], 16 KB

    const int tid  = threadIdx.x;
    const int lane = tid & 63;
    const int wv   = tid >> 6;              // 0..3
    const int c31  = lane & 31;
    const int half = lane >> 5;             // 0/1

    const int g  = blockIdx.x;              // 0..1535
    const int bc = g >> 4;                  // 0..95
    const int hb = ((g & 15) << 2) + wv;    // 4 consecutive hb per WG

    // ---- stage hi/lo A-fragments into LDS (round-14 verified) ----
    // F=((kt*4+nc)*2+p): lane l elem j = basis[kt*32+(l&31)][nc*16+(l>>5)*8+j]
    #pragma unroll
    for (int r = 0; r < 4; ++r) {
        const int s  = tid + (r << 8);         // 0..1023
        const int F  = s >> 6;                 // wave-uniform
        const int ln = s & 63;
        const int k  = ((F >> 3) << 5) + (ln & 31);
        const int n  = (((F >> 1) & 3) << 4) + ((ln >> 5) << 3);
        const float4 v0 = *reinterpret_cast<const float4*>(basis + k * 64 + n);
        const float4 v1 = *reinterpret_cast<const float4*>(basis + k * 64 + n + 4);
        const float vv[8] = {v0.x, v0.y, v0.z, v0.w, v1.x, v1.y, v1.z, v1.w};
        bf16x8 f;
        if (F & 1) {
            #pragma unroll
            for (int j = 0; j < 8; ++j) {
                const __bf16 h = (__bf16)vv[j];
                f[j] = (__bf16)(vv[j] - (float)h);
            }
        } else {
            #pragma unroll
            for (int j = 0; j < 8; ++j)
                f[j] = (__bf16)vv[j];
        }
        Alds[s] = f;
    }
    __syncthreads();

#define ALD(F) Alds[((F) << 6) + lane]

    // B: wb-half A = blocks c31 (wb 0..31), wb-half B = blocks 32+c31.
    const float* xpA = x + ((size_t)bc << 18) + ((size_t)hb << 12) + (c31 << 3);
    const float* xpB = xpA + (32 << 3);

    f32x16 aA0 = {0.f}, aA1 = {0.f}, aB0 = {0.f}, aB1 = {0.f};
    #pragma unroll
    for (int nc = 0; nc < 4; ++nc) {
        const int i = nc * 2 + half;
        const float4 a0 = *reinterpret_cast<const float4*>(xpA + i * 512);
        const float4 a1 = *reinterpret_cast<const float4*>(xpA + i * 512 + 4);
        const float4 b0 = *reinterpret_cast<const float4*>(xpB + i * 512);
        const float4 b1 = *reinterpret_cast<const float4*>(xpB + i * 512 + 4);
        bf16x8 XhA, XlA, XhB, XlB;
        MAKE_BX(a0, a1, XhA, XlA)
        MAKE_BX(b0, b1, XhB, XlB)
        const bf16x8 A0h = ALD((0 * 4 + nc) * 2 + 0);
        const bf16x8 A1h = ALD((1 * 4 + nc) * 2 + 0);
        const bf16x8 A0l = ALD((0 * 4 + nc) * 2 + 1);
        const bf16x8 A1l = ALD((1 * 4 + nc) * 2 + 1);
        aA0 = mfma32(A0h, XhA, aA0);   // bh*xh, k 0..31, wb half A
        aB0 = mfma32(A0h, XhB, aB0);
        aA1 = mfma32(A1h, XhA, aA1);   // k 32..63
        aB1 = mfma32(A1h, XhB, aB1);
        aA0 = mfma32(A0h, XlA, aA0);   // bh*xl
        aB0 = mfma32(A0h, XlB, aB0);
        aA1 = mfma32(A1h, XlA, aA1);
        aB1 = mfma32(A1h, XlB, aB1);
        aA0 = mfma32(A0l, XhA, aA0);   // bl*xh
        aB0 = mfma32(A0l, XhB, aB0);
        aA1 = mfma32(A1l, XhA, aA1);
        aB1 = mfma32(A1l, XhB, aB1);
    }

    // D: reg r -> row (r&3)+8*(r>>2)+4*half, col c31 (m74/m101-verified).
    // Per r: 4 adjacent stores complete 256B rows k=row and k=row+32.
    float* ob = out + ((size_t)bc << 18) + (hb << 6);
    #pragma unroll
    for (int r = 0; r < 16; ++r) {
        const int row = (r & 3) + ((r >> 2) << 3) + (half << 2);
        float* p0 = ob + ((size_t)row << 12) + c31;
        float* p1 = ob + ((size_t)(row + 32) << 12) + c31;
        __builtin_nontemporal_store(aA0[r], p0);
        __builtin_nontemporal_store(aB0[r], p0 + 32);
        __builtin_nontemporal_store(aA1[r], p1);
        __builtin_nontemporal_store(aB1[r], p1 + 32);
    }
}

extern "C" void kernel_launch(void* const* d_in, const int* in_sizes, int n_in,
                              void* d_out, int out_size, void* d_ws, size_t ws_size,
                              hipStream_t stream) {
    const float* x     = (const float*)d_in[0];
    const float* basis = (const float*)d_in[1];
    float* out         = (float*)d_out;

    // 96 bc * 16 hb-quartets = 1536 WGs; wave = full row (2 tiles)
    dct_mfma<<<dim3(1536), dim3(256), 0, stream>>>(x, basis, out);
}